// Round 5
// baseline (204.330 us; speedup 1.0000x reference)
//
#include <hip/hip_runtime.h>
#include <hip/hip_bf16.h>
#include <stdint.h>

#define B_DIM   4096
#define IN_DIM  4096
#define OUT_DIM 4096
#define K_SEL   128

typedef unsigned short u16;
typedef __bf16 bf16x8 __attribute__((ext_vector_type(8)));
typedef float  f32x4  __attribute__((ext_vector_type(4)));

static __device__ __forceinline__ u16 f2bf(float f) {
    uint32_t u = __builtin_bit_cast(uint32_t, f);
    uint32_t r = (u + 0x7fffu + ((u >> 16) & 1u)) >> 16;
    return (u16)r;
}

// ---------------------------------------------------------------------------
// K1: column sums of W (fp64 partials over 8-row chunks) + W -> bf16.
// 2048 blocks = (4 col-chunks x 512 row-chunks) x 256 threads; float4 loads.
// part = [512][4096] doubles (16MB) in d_out, consumed before gemm writes.
// ---------------------------------------------------------------------------
__global__ __launch_bounds__(256) void colsum_conv(const float* __restrict__ W,
                                                   double* __restrict__ part,
                                                   u16* __restrict__ Wb) {
    int cb = blockIdx.x & 3;
    int rb = blockIdx.x >> 2;          // 0..511
    int c4 = cb * 256 + threadIdx.x;   // float4 index within a row
    int row0 = rb * 8;
    double s0 = 0.0, s1 = 0.0, s2 = 0.0, s3 = 0.0;
    for (int r = 0; r < 8; ++r) {
        const float4 v = ((const float4*)(W + (size_t)(row0 + r) * IN_DIM))[c4];
        s0 += (double)v.x; s1 += (double)v.y; s2 += (double)v.z; s3 += (double)v.w;
        ushort4 o;
        o.x = f2bf(v.x); o.y = f2bf(v.y); o.z = f2bf(v.z); o.w = f2bf(v.w);
        ((ushort4*)(Wb + (size_t)(row0 + r) * IN_DIM))[c4] = o;
    }
    double4 d; d.x = s0; d.y = s1; d.z = s2; d.w = s3;
    ((double4*)(part + (size_t)rb * IN_DIM))[c4] = d;
}

__global__ __launch_bounds__(256) void colsum_final(const double* __restrict__ part,
                                                    float* __restrict__ cs) {
    int col = blockIdx.x * 256 + threadIdx.x;
    double s = 0.0;
    for (int r = 0; r < 512; ++r) s += part[(size_t)r * IN_DIM + col];
    cs[col] = (float)s;
}

// ---------------------------------------------------------------------------
// K3: per-row top-128 of |x*colsum| via 4-pass radix select, exact ties
// (lowest index first), write masked x as bf16. One 256-thread block per row.
// ---------------------------------------------------------------------------
__global__ __launch_bounds__(256) void topk_mask(const float* __restrict__ x,
                                                 const float* __restrict__ cs,
                                                 u16* __restrict__ xz) {
    __shared__ uint32_t hist[256];
    __shared__ uint32_t suf[256];
    __shared__ uint32_t s_scan[256];
    __shared__ uint32_t s_prefix, s_krem;

    const int b = blockIdx.x, t = threadIdx.x;
    const float4* xrow = (const float4*)(x + (size_t)b * IN_DIM);
    const float4* csv  = (const float4*)cs;

    float    xr[16];
    uint32_t ul[16];
#pragma unroll
    for (int q = 0; q < 4; ++q) {
        float4 xv = xrow[t * 4 + q];
        float4 cv = csv[t * 4 + q];
        xr[q*4+0] = xv.x; xr[q*4+1] = xv.y; xr[q*4+2] = xv.z; xr[q*4+3] = xv.w;
        ul[q*4+0] = __builtin_bit_cast(uint32_t, xv.x * cv.x) & 0x7fffffffu;
        ul[q*4+1] = __builtin_bit_cast(uint32_t, xv.y * cv.y) & 0x7fffffffu;
        ul[q*4+2] = __builtin_bit_cast(uint32_t, xv.z * cv.z) & 0x7fffffffu;
        ul[q*4+3] = __builtin_bit_cast(uint32_t, xv.w * cv.w) & 0x7fffffffu;
    }
    if (t == 0) { s_prefix = 0u; s_krem = K_SEL; }
    __syncthreads();

#pragma unroll
    for (int p = 3; p >= 0; --p) {
        const int sh = p * 8;
        const uint32_t hi_mask = (p == 3) ? 0u : (0xFFFFFFFFu << (sh + 8));
        const uint32_t prefix = s_prefix;
        const uint32_t krem   = s_krem;
        hist[t] = 0u;
        __syncthreads();
#pragma unroll
        for (int j = 0; j < 16; ++j) {
            uint32_t u = ul[j];
            if ((u & hi_mask) == (prefix & hi_mask))
                atomicAdd(&hist[(u >> sh) & 255u], 1u);
        }
        __syncthreads();
        uint32_t mine = hist[t];
        suf[t] = mine;
        __syncthreads();
#pragma unroll
        for (int off = 1; off < 256; off <<= 1) {
            uint32_t other = (t + off < 256) ? suf[t + off] : 0u;
            __syncthreads();
            mine += other;
            suf[t] = mine;
            __syncthreads();
        }
        uint32_t mysuf   = suf[t];
        uint32_t nextsuf = (t < 255) ? suf[t + 1] : 0u;
        if (mysuf >= krem && (t == 255 || nextsuf < krem)) {
            s_prefix = prefix | ((uint32_t)t << sh);
            s_krem   = krem - nextsuf;
        }
        __syncthreads();
    }
    const uint32_t T       = s_prefix;
    const uint32_t need_eq = s_krem;

    int cnt = 0;
#pragma unroll
    for (int j = 0; j < 16; ++j) cnt += (ul[j] == T) ? 1 : 0;
    s_scan[t] = (uint32_t)cnt;
    __syncthreads();
    uint32_t inc = (uint32_t)cnt;
#pragma unroll
    for (int off = 1; off < 256; off <<= 1) {
        uint32_t other = (t >= off) ? s_scan[t - off] : 0u;
        __syncthreads();
        inc += other;
        s_scan[t] = inc;
        __syncthreads();
    }
    const int base = (int)(inc - (uint32_t)cnt);

    union { u16 us[16]; uint4 v[2]; } ob;
    int eqseen = 0;
#pragma unroll
    for (int j = 0; j < 16; ++j) {
        uint32_t u = ul[j];
        bool drop = (u > T);
        if (u == T) {
            if (base + eqseen < (int)need_eq) drop = true;
            ++eqseen;
        }
        ob.us[j] = drop ? (u16)0 : f2bf(xr[j]);
    }
    uint4* dst = (uint4*)(xz + (size_t)b * IN_DIM + t * 16);
    dst[0] = ob.v[0];
    dst[1] = ob.v[1];
}

// ---------------------------------------------------------------------------
// K4: bf16 GEMM C = A @ B^T, 256x256 tile, BK=64, 8 waves (2Mx4N),
// SOFTWARE-PIPELINED register fragments + 2 barriers/tile:
//   phase p issues ds_reads for phase p+1's frags; MFMA p consumes frags
//   loaded at p-1 (compiler emits counted lgkm waits -> ~zero stall).
//   phases: p0=(qm0,ks0) p1=(qm1,ks0) p2=(qm0,ks1) p3=(qm1,ks1).
// Staging: ALL 8 gloads for tile k+1 issued at k p0 into bufn.
//   barrier 1 (p2-end): vmcnt(0)+s_barrier publishes tile k+1 (loads ~2
//   phases old -> drain ~free); k p3 then read-aheads k+1 p0's frags.
//   barrier 2 (tile end): orders k+1 p0's stages (into buf k) after ALL
//   waves' last buf(k) reads (done by each wave's own p3 MFMA dep-wait).
// T2 XOR-swizzle (0 conflicts), T5 setprio, sched_barrier(0) between phases.
// ---------------------------------------------------------------------------
#define NT 64

__global__ __launch_bounds__(512, 2) void gemm_pl(const u16* __restrict__ A,
                                                  const u16* __restrict__ Bm,
                                                  float* __restrict__ C) {
    __shared__ u16 lds_[65536];   // 128 KB

    const int bid = blockIdx.x;
    const int swz = (bid & 7) * 32 + (bid >> 3);   // 256 blocks, 8 XCDs
    const int m0 = (swz >> 4) * 256, n0 = (swz & 15) * 256;

    const int t = threadIdx.x;
    const int l = t & 63;
    const int lr = l & 15, lk = l >> 4;
    const int w = t >> 6;
    const int wm = w >> 2, wn = w & 3;

    const int cswz = ((t & 7) ^ ((t >> 3) & 7)) * 8;   // staging src col (elems)
    const int c0   = (lk ^ (lr & 7)) * 8;              // swizzled col, ks=0
    const int c1   = c0 ^ 32;                          // ks=1

    f32x4 acc[8][4];
#pragma unroll
    for (int i = 0; i < 8; ++i)
#pragma unroll
        for (int j = 0; j < 4; ++j) acc[i][j] = f32x4{0.f, 0.f, 0.f, 0.f};

#define GLOAD(g, off_bytes)                                                     \
    __builtin_amdgcn_global_load_lds(                                           \
        (const __attribute__((address_space(1))) void*)(g),                     \
        (__attribute__((address_space(3))) void*)(((char*)lds_) + (off_bytes)), \
        16, 0, 0)

    // stage A region qm (packed rows g*128+qm*64+(t>>3)), 16KB = 2 gloads
    auto stA = [&](int kb, int qm, int kt) {
#pragma unroll
        for (int g = 0; g < 2; ++g)
            GLOAD(A + (size_t)(m0 + g * 128 + qm * 64 + (t >> 3)) * IN_DIM + kt + cswz,
                  kb * 65536 + qm * 16384 + g * 8192 + t * 16);
    };
    // stage B region qn (packed rows (g*2+(t>>8))*64+qn*32+((t>>3)&31))
    auto stB = [&](int kb, int qn, int kt) {
#pragma unroll
        for (int g = 0; g < 2; ++g)
            GLOAD(Bm + (size_t)(n0 + (g * 2 + (t >> 8)) * 64 + qn * 32 + ((t >> 3) & 31)) * IN_DIM + kt + cswz,
                  kb * 65536 + 32768 + qn * 16384 + g * 8192 + t * 16);
    };

    // frag reads (element offsets into lds_): A(qm,mi): bufo+qm*8192+wm*4096
    // +lr*64+mi*1024+c ; B(ni): bufo+16384+(ni>>1)*8192+wn*2048+lr*64+(ni&1)*1024+c
    auto rdA = [&](bf16x8 (&dst)[4], int bufo, int qm, int c) {
#pragma unroll
        for (int mi = 0; mi < 4; ++mi)
            dst[mi] = *(const bf16x8*)&lds_[bufo + qm * 8192 + wm * 4096 + lr * 64 + mi * 1024 + c];
    };
    auto rdB = [&](bf16x8 (&dst)[4], int bufo, int c) {
#pragma unroll
        for (int ni = 0; ni < 4; ++ni)
            dst[ni] = *(const bf16x8*)&lds_[bufo + 16384 + (ni >> 1) * 8192 + wn * 2048 + lr * 64 + (ni & 1) * 1024 + c];
    };
    auto mm = [&](int base, bf16x8 (&Aa)[4], bf16x8 (&Bb)[4]) {
#pragma unroll
        for (int mi = 0; mi < 4; ++mi)
#pragma unroll
            for (int ni = 0; ni < 4; ++ni)
                acc[base + mi][ni] = __builtin_amdgcn_mfma_f32_16x16x32_bf16(
                    Aa[mi], Bb[ni], acc[base + mi][ni], 0, 0, 0);
    };

    bf16x8 aX[4], aY[4], bX[4], bY[4];

    // prologue: stage tile0 -> buf0, publish, pre-read p0 frags
    stA(0, 0, 0); stA(0, 1, 0); stB(0, 0, 0); stB(0, 1, 0);
    asm volatile("s_waitcnt vmcnt(0)" ::: "memory");
    __builtin_amdgcn_s_barrier();
    asm volatile("" ::: "memory");
    rdA(aX, 0, 0, c0);   // A0 ks0
    rdB(bX, 0, c0);      // B  ks0

    for (int k = 0; k < NT; ++k) {
        const int bufo = (k & 1) * 32768, bufno = bufo ^ 32768;  // elems
        const int kbn  = (k & 1) ^ 1;                            // staging buf idx
        const int kt1  = (k + 1) * 64;

        // ---- p0 (qm0,ks0): read p1 frags; stage ALL of tile k+1 -> bufn ----
        rdA(aY, bufo, 1, c0);                          // A1 ks0
        if (k < NT - 1) {
            stA(kbn, 0, kt1); stA(kbn, 1, kt1);
            stB(kbn, 0, kt1); stB(kbn, 1, kt1);
        }
        __builtin_amdgcn_s_setprio(1);
        mm(0, aX, bX);
        __builtin_amdgcn_s_setprio(0);
        __builtin_amdgcn_sched_barrier(0);

        // ---- p1 (qm1,ks0): read p2 frags ----
        rdA(aX, bufo, 0, c1);                          // A0 ks1
        rdB(bY, bufo, c1);                             // B  ks1
        __builtin_amdgcn_s_setprio(1);
        mm(4, aY, bX);
        __builtin_amdgcn_s_setprio(0);
        __builtin_amdgcn_sched_barrier(0);

        // ---- p2 (qm0,ks1): read p3 frags; then publish tile k+1 ----
        rdA(aY, bufo, 1, c1);                          // A1 ks1
        __builtin_amdgcn_s_setprio(1);
        mm(0, aX, bY);
        __builtin_amdgcn_s_setprio(0);
        __builtin_amdgcn_sched_barrier(0);
        asm volatile("s_waitcnt vmcnt(0)" ::: "memory");
        __builtin_amdgcn_s_barrier();
        asm volatile("" ::: "memory");

        // ---- p3 (qm1,ks1): read-ahead next tile's p0 frags from bufn ----
        if (k < NT - 1) {
            rdA(aX, bufno, 0, c0);
            rdB(bX, bufno, c0);
        }
        __builtin_amdgcn_s_setprio(1);
        mm(4, aY, bY);
        __builtin_amdgcn_s_setprio(0);
        __builtin_amdgcn_sched_barrier(0);
        asm volatile("" ::: "memory");
        __builtin_amdgcn_s_barrier();
        asm volatile("" ::: "memory");
    }
#undef GLOAD

    // epilogue: C/D layout col = lane&15, row = (lane>>4)*4 + r
#pragma unroll
    for (int gmi = 0; gmi < 8; ++gmi)
#pragma unroll
        for (int ni = 0; ni < 4; ++ni)
#pragma unroll
            for (int r = 0; r < 4; ++r) {
                int row = m0 + wm * 128 + (gmi >> 2) * 64 + (gmi & 3) * 16 + lk * 4 + r;
                int col = n0 + wn * 64 + ni * 16 + lr;
                C[(size_t)row * OUT_DIM + col] = acc[gmi][ni][r];
            }
}

// ---------------------------------------------------------------------------
extern "C" void kernel_launch(void* const* d_in, const int* in_sizes, int n_in,
                              void* d_out, int out_size, void* d_ws, size_t ws_size,
                              hipStream_t stream) {
    const float* x = (const float*)d_in[0];
    const float* W = (const float*)d_in[1];
    float* out = (float*)d_out;

    char* ws = (char*)d_ws;
    u16*    Wb   = (u16*)ws;                                   // 32 MB bf16 W
    u16*    xz   = (u16*)(ws + (size_t)32 * 1024 * 1024);      // 32 MB bf16 masked x
    float*  cs   = (float*)(ws + (size_t)64 * 1024 * 1024);    // 16 KB colsum
    double* part = (double*)d_out;  // 16 MB partials, consumed before gemm writes

    colsum_conv<<<2048, 256, 0, stream>>>(W, part, Wb);
    colsum_final<<<16, 256, 0, stream>>>(part, cs);
    topk_mask<<<4096, 256, 0, stream>>>(x, cs, xz);
    gemm_pl<<<256, 512, 0, stream>>>(xz, Wb, out);
}

// Round 7
// 188.692 us; speedup vs baseline: 1.0829x; 1.0829x over previous
//
#include <hip/hip_runtime.h>
#include <hip/hip_bf16.h>
#include <stdint.h>

#define B_DIM   4096
#define IN_DIM  4096
#define OUT_DIM 4096
#define K_SEL   128

typedef unsigned short u16;
typedef __bf16 bf16x8 __attribute__((ext_vector_type(8)));
typedef float  f32x4  __attribute__((ext_vector_type(4)));

static __device__ __forceinline__ u16 f2bf(float f) {
    uint32_t u = __builtin_bit_cast(uint32_t, f);
    uint32_t r = (u + 0x7fffu + ((u >> 16) & 1u)) >> 16;
    return (u16)r;
}

// ---------------------------------------------------------------------------
// K1: column sums of W (fp64 partials over 8-row chunks) + W -> bf16.
// 2048 blocks; float4 loads. part = [512][4096] doubles (16MB) in d_out.
// ---------------------------------------------------------------------------
__global__ __launch_bounds__(256) void colsum_conv(const float* __restrict__ W,
                                                   double* __restrict__ part,
                                                   u16* __restrict__ Wb) {
    int cb = blockIdx.x & 3;
    int rb = blockIdx.x >> 2;          // 0..511
    int c4 = cb * 256 + threadIdx.x;   // float4 index within a row
    int row0 = rb * 8;
    double s0 = 0.0, s1 = 0.0, s2 = 0.0, s3 = 0.0;
    for (int r = 0; r < 8; ++r) {
        const float4 v = ((const float4*)(W + (size_t)(row0 + r) * IN_DIM))[c4];
        s0 += (double)v.x; s1 += (double)v.y; s2 += (double)v.z; s3 += (double)v.w;
        ushort4 o;
        o.x = f2bf(v.x); o.y = f2bf(v.y); o.z = f2bf(v.z); o.w = f2bf(v.w);
        ((ushort4*)(Wb + (size_t)(row0 + r) * IN_DIM))[c4] = o;
    }
    double4 d; d.x = s0; d.y = s1; d.z = s2; d.w = s3;
    ((double4*)(part + (size_t)rb * IN_DIM))[c4] = d;
}

// 256 blocks x 256 threads: block handles 16 cols; 16 row-groups of 32.
__global__ __launch_bounds__(256) void colsum_final(const double* __restrict__ part,
                                                    float* __restrict__ cs) {
    __shared__ double red[256];
    const int t = threadIdx.x;
    const int c = blockIdx.x * 16 + (t & 15);
    const int g = t >> 4;              // 0..15
    double s = 0.0;
    for (int r = 0; r < 32; ++r) s += part[(size_t)(g * 32 + r) * IN_DIM + c];
    red[t] = s;
    __syncthreads();
    for (int off = 128; off >= 16; off >>= 1) {
        if (t < off) red[t] += red[t + off];
        __syncthreads();
    }
    if (t < 16) cs[blockIdx.x * 16 + t] = (float)red[t];
}

// ---------------------------------------------------------------------------
// K3: per-row top-128 of |x*colsum| via 4-pass radix select, exact ties
// (lowest index first), write masked x as bf16. One 256-thread block per row.
// ---------------------------------------------------------------------------
__global__ __launch_bounds__(256) void topk_mask(const float* __restrict__ x,
                                                 const float* __restrict__ cs,
                                                 u16* __restrict__ xz) {
    __shared__ uint32_t hist[256];
    __shared__ uint32_t suf[256];
    __shared__ uint32_t s_scan[256];
    __shared__ uint32_t s_prefix, s_krem;

    const int b = blockIdx.x, t = threadIdx.x;
    const float4* xrow = (const float4*)(x + (size_t)b * IN_DIM);
    const float4* csv  = (const float4*)cs;

    float    xr[16];
    uint32_t ul[16];
#pragma unroll
    for (int q = 0; q < 4; ++q) {
        float4 xv = xrow[t * 4 + q];
        float4 cv = csv[t * 4 + q];
        xr[q*4+0] = xv.x; xr[q*4+1] = xv.y; xr[q*4+2] = xv.z; xr[q*4+3] = xv.w;
        ul[q*4+0] = __builtin_bit_cast(uint32_t, xv.x * cv.x) & 0x7fffffffu;
        ul[q*4+1] = __builtin_bit_cast(uint32_t, xv.y * cv.y) & 0x7fffffffu;
        ul[q*4+2] = __builtin_bit_cast(uint32_t, xv.z * cv.z) & 0x7fffffffu;
        ul[q*4+3] = __builtin_bit_cast(uint32_t, xv.w * cv.w) & 0x7fffffffu;
    }
    if (t == 0) { s_prefix = 0u; s_krem = K_SEL; }
    __syncthreads();

#pragma unroll
    for (int p = 3; p >= 0; --p) {
        const int sh = p * 8;
        const uint32_t hi_mask = (p == 3) ? 0u : (0xFFFFFFFFu << (sh + 8));
        const uint32_t prefix = s_prefix;
        const uint32_t krem   = s_krem;
        hist[t] = 0u;
        __syncthreads();
#pragma unroll
        for (int j = 0; j < 16; ++j) {
            uint32_t u = ul[j];
            if ((u & hi_mask) == (prefix & hi_mask))
                atomicAdd(&hist[(u >> sh) & 255u], 1u);
        }
        __syncthreads();
        uint32_t mine = hist[t];
        suf[t] = mine;
        __syncthreads();
#pragma unroll
        for (int off = 1; off < 256; off <<= 1) {
            uint32_t other = (t + off < 256) ? suf[t + off] : 0u;
            __syncthreads();
            mine += other;
            suf[t] = mine;
            __syncthreads();
        }
        uint32_t mysuf   = suf[t];
        uint32_t nextsuf = (t < 255) ? suf[t + 1] : 0u;
        if (mysuf >= krem && (t == 255 || nextsuf < krem)) {
            s_prefix = prefix | ((uint32_t)t << sh);
            s_krem   = krem - nextsuf;
        }
        __syncthreads();
    }
    const uint32_t T       = s_prefix;
    const uint32_t need_eq = s_krem;

    int cnt = 0;
#pragma unroll
    for (int j = 0; j < 16; ++j) cnt += (ul[j] == T) ? 1 : 0;
    s_scan[t] = (uint32_t)cnt;
    __syncthreads();
    uint32_t inc = (uint32_t)cnt;
#pragma unroll
    for (int off = 1; off < 256; off <<= 1) {
        uint32_t other = (t >= off) ? s_scan[t - off] : 0u;
        __syncthreads();
        inc += other;
        s_scan[t] = inc;
        __syncthreads();
    }
    const int base = (int)(inc - (uint32_t)cnt);

    union { u16 us[16]; uint4 v[2]; } ob;
    int eqseen = 0;
#pragma unroll
    for (int j = 0; j < 16; ++j) {
        uint32_t u = ul[j];
        bool drop = (u > T);
        if (u == T) {
            if (base + eqseen < (int)need_eq) drop = true;
            ++eqseen;
        }
        ob.us[j] = drop ? (u16)0 : f2bf(xr[j]);
    }
    uint4* dst = (uint4*)(xz + (size_t)b * IN_DIM + t * 16);
    dst[0] = ob.v[0];
    dst[1] = ob.v[1];
}

// ---------------------------------------------------------------------------
// K4: bf16 GEMM C = A @ B^T, 256x256 tile, BK=64, 8 waves (2Mx4N).
// Pipelined frags + spread counted staging (T3+T4):
//   MFMA phases P0=(qm0,ks0) P1=(qm0,ks1) P2=(qm1,ks0) P3=(qm1,ks1), 16
//   independent MFMAs each, consuming frags read in the PREVIOUS phase.
//   Reads: P0: a0k1+bk1 (8) | P1: a1k0+a1k1 (8) | P2: none | P3: a0k0+bk0 of
//   tile k+1 from bufN (8, after the publish barrier).
// LDS = 2 bufs x 64KB (BYTE stride 65536  <-- r6 bug was 131072 = OOB).
//   Regions per buf: A-r0 @0, A-r1 @16K, B-r0 @32K, B-r1 @48K.
// Stage-units (16KB = 2 gloads): S4(k+1)=A-r1@P0, S1(k+2)=A-r0@P1,
// S2(k+2)=B-r0@P2, S3(k+2)=B-r1@P3.
// Publish tile k+1 at P2(k): vmcnt(4) keeps exactly {S1(k+2),S2(k+2)} and
// drains all 8 gloads of tile k+1 (inductive; prologue vmcnt(6) seeds it).
// vmcnt(0) for k>=NT-2 (units not issued at tail). Phase end =
// lgkmcnt(0)+s_barrier => every stage-write-vs-frag-read WAR is
// barrier-separated. T2 XOR-swizzle (0 conflicts), T5 setprio.
// ---------------------------------------------------------------------------
#define NT 64

__global__ __launch_bounds__(512, 2) void gemm_pl(const u16* __restrict__ A,
                                                  const u16* __restrict__ Bm,
                                                  float* __restrict__ C) {
    __shared__ u16 lds_[65536];   // 128 KB

    const int bid = blockIdx.x;
    const int swz = (bid & 7) * 32 + (bid >> 3);   // 256 blocks, 8 XCDs
    const int m0 = (swz >> 4) * 256, n0 = (swz & 15) * 256;

    const int t = threadIdx.x;
    const int l = t & 63;
    const int lr = l & 15, lk = l >> 4;
    const int w = t >> 6;
    const int wm = w >> 2, wn = w & 3;

    const int cswz = ((t & 7) ^ ((t >> 3) & 7)) * 8;   // staging src col (elems)
    const int c0   = (lk ^ (lr & 7)) * 8;              // swizzled col, ks=0
    const int c1   = c0 ^ 32;                          // ks=1

    f32x4 acc[8][4];
#pragma unroll
    for (int i = 0; i < 8; ++i)
#pragma unroll
        for (int j = 0; j < 4; ++j) acc[i][j] = f32x4{0.f, 0.f, 0.f, 0.f};

#define GLOAD(g, off_bytes)                                                     \
    __builtin_amdgcn_global_load_lds(                                           \
        (const __attribute__((address_space(1))) void*)(g),                     \
        (__attribute__((address_space(3))) void*)(((char*)lds_) + (off_bytes)), \
        16, 0, 0)

    // A region r: rows {g*128 + r*64 .. +64} for g=0,1 -> 16KB
    auto stA = [&](int kb, int r, int kt) {
#pragma unroll
        for (int g = 0; g < 2; ++g)
            GLOAD(A + (size_t)(m0 + g * 128 + r * 64 + (t >> 3)) * IN_DIM + kt + cswz,
                  kb * 65536 + r * 16384 + g * 8192 + t * 16);
    };
    // B region r: rows {r*128 + g*64 .. +64} for g=0,1 -> 16KB
    auto stB = [&](int kb, int r, int kt) {
#pragma unroll
        for (int g = 0; g < 2; ++g)
            GLOAD(Bm + (size_t)(n0 + r * 128 + g * 64 + (t >> 3)) * IN_DIM + kt + cswz,
                  kb * 65536 + 32768 + r * 16384 + g * 8192 + t * 16);
    };

    // frag reads (elem offsets): A(qm,mi): bufo + qm*8192 + wm*4096 + lr*64
    //  + mi*1024 + c ; B(ni): bufo + 16384 + (wn>>1)*8192 + (wn&1)*4096
    //  + lr*64 + ni*1024 + c
    auto rdA = [&](bf16x8 (&dst)[4], int bufo, int qm, int c) {
#pragma unroll
        for (int mi = 0; mi < 4; ++mi)
            dst[mi] = *(const bf16x8*)&lds_[bufo + qm * 8192 + wm * 4096 + lr * 64 + mi * 1024 + c];
    };
    auto rdB = [&](bf16x8 (&dst)[4], int bufo, int c) {
#pragma unroll
        for (int ni = 0; ni < 4; ++ni)
            dst[ni] = *(const bf16x8*)&lds_[bufo + 16384 + (wn >> 1) * 8192 + (wn & 1) * 4096 + lr * 64 + ni * 1024 + c];
    };
    auto mm = [&](int base, bf16x8 (&Aa)[4], bf16x8 (&Bb)[4]) {
        __builtin_amdgcn_s_setprio(1);
#pragma unroll
        for (int mi = 0; mi < 4; ++mi)
#pragma unroll
            for (int ni = 0; ni < 4; ++ni)
                acc[base + mi][ni] = __builtin_amdgcn_mfma_f32_16x16x32_bf16(
                    Aa[mi], Bb[ni], acc[base + mi][ni], 0, 0, 0);
        __builtin_amdgcn_s_setprio(0);
        __builtin_amdgcn_sched_barrier(0);
    };

    bf16x8 a0k0[4], a0k1[4], a1k0[4], a1k1[4], bk0[4], bk1[4];

    // prologue: tile0 complete + S1..S3(1); vmcnt(6) leaves exactly those 6;
    // publish tile0; pre-read P0's frags.
    stA(0, 0, 0); stA(0, 1, 0); stB(0, 0, 0); stB(0, 1, 0);
    stA(1, 0, 64); stB(1, 0, 64); stB(1, 1, 64);
    asm volatile("s_waitcnt vmcnt(6)" ::: "memory");
    __builtin_amdgcn_s_barrier();
    asm volatile("" ::: "memory");
    rdA(a0k0, 0, 0, c0);
    rdB(bk0, 0, c0);

    for (int k = 0; k < NT; ++k) {
        const int bufo = (k & 1) * 32768;               // elem offset
        const int bufno = bufo ^ 32768;
        const int kbC = k & 1, kbN = kbC ^ 1;
        const int kt1 = (k + 1) * 64, kt2 = (k + 2) * 64;

        // ---- P0 (qm0,ks0): reads a0k1,bk1(k); stage S4(k+1)=A-r1 -> bufN ----
        rdA(a0k1, bufo, 0, c1);
        rdB(bk1, bufo, c1);
        if (k < NT - 1) stA(kbN, 1, kt1);
        mm(0, a0k0, bk0);
        asm volatile("s_waitcnt lgkmcnt(0)" ::: "memory");
        __builtin_amdgcn_s_barrier();
        asm volatile("" ::: "memory");

        // ---- P1 (qm0,ks1): reads a1k0,a1k1(k); stage S1(k+2)=A-r0 -> bufC ----
        rdA(a1k0, bufo, 1, c0);
        rdA(a1k1, bufo, 1, c1);
        if (k < NT - 2) stA(kbC, 0, kt2);
        mm(0, a0k1, bk1);
        asm volatile("s_waitcnt lgkmcnt(0)" ::: "memory");
        __builtin_amdgcn_s_barrier();
        asm volatile("" ::: "memory");

        // ---- P2 (qm1,ks0): no reads; stage S2(k+2)=B-r0 -> bufC; publish ----
        if (k < NT - 2) stB(kbC, 0, kt2);
        mm(4, a1k0, bk0);
        if (k < NT - 2) {
            asm volatile("s_waitcnt vmcnt(4) lgkmcnt(0)" ::: "memory");
        } else {
            asm volatile("s_waitcnt vmcnt(0) lgkmcnt(0)" ::: "memory");
        }
        __builtin_amdgcn_s_barrier();
        asm volatile("" ::: "memory");

        // ---- P3 (qm1,ks1): reads a0k0,bk0(k+1) from bufN; stage S3(k+2) ----
        if (k < NT - 1) {
            rdA(a0k0, bufno, 0, c0);
            rdB(bk0, bufno, c0);
        }
        if (k < NT - 2) stB(kbC, 1, kt2);
        mm(4, a1k1, bk1);
        asm volatile("s_waitcnt lgkmcnt(0)" ::: "memory");
        __builtin_amdgcn_s_barrier();
        asm volatile("" ::: "memory");
    }
#undef GLOAD

    // epilogue: C/D layout col = lane&15, row = (lane>>4)*4 + r
#pragma unroll
    for (int gmi = 0; gmi < 8; ++gmi)
#pragma unroll
        for (int ni = 0; ni < 4; ++ni)
#pragma unroll
            for (int r = 0; r < 4; ++r) {
                int row = m0 + wm * 128 + (gmi >> 2) * 64 + (gmi & 3) * 16 + lk * 4 + r;
                int col = n0 + wn * 64 + ni * 16 + lr;
                C[(size_t)row * OUT_DIM + col] = acc[gmi][ni][r];
            }
}

// ---------------------------------------------------------------------------
extern "C" void kernel_launch(void* const* d_in, const int* in_sizes, int n_in,
                              void* d_out, int out_size, void* d_ws, size_t ws_size,
                              hipStream_t stream) {
    const float* x = (const float*)d_in[0];
    const float* W = (const float*)d_in[1];
    float* out = (float*)d_out;

    char* ws = (char*)d_ws;
    u16*    Wb   = (u16*)ws;                                   // 32 MB bf16 W
    u16*    xz   = (u16*)(ws + (size_t)32 * 1024 * 1024);      // 32 MB bf16 masked x
    float*  cs   = (float*)(ws + (size_t)64 * 1024 * 1024);    // 16 KB colsum
    double* part = (double*)d_out;  // 16 MB partials, consumed before gemm writes

    colsum_conv<<<2048, 256, 0, stream>>>(W, part, Wb);
    colsum_final<<<256, 256, 0, stream>>>(part, cs);
    topk_mask<<<4096, 256, 0, stream>>>(x, cs, xz);
    gemm_pl<<<256, 512, 0, stream>>>(xz, Wb, out);
}